// Round 8
// baseline (390.125 us; speedup 1.0000x reference)
//
#include <hip/hip_runtime.h>
#include <hip/hip_bf16.h>
#include <stdint.h>

#define M_DIM 4096
#define N_DIM 4096
#define K_DIM 4096
#define NTO 64  // orig K-tiles of 64

typedef float f32x4 __attribute__((ext_vector_type(4)));
typedef __bf16 bf16x8 __attribute__((ext_vector_type(8)));
typedef float f4 __attribute__((ext_vector_type(4)));
typedef unsigned int u32x4 __attribute__((ext_vector_type(4)));
typedef unsigned short u16x8 __attribute__((ext_vector_type(8)));

__device__ __forceinline__ uint16_t f32_to_bf16_rn(float f) {
  uint32_t u = __float_as_uint(f);
  u += 0x7fffu + ((u >> 16) & 1u);
  return (uint16_t)(u >> 16);
}

// ---------- fused: W -> sign(W) bf16 ; x -> A' = [x_hi | x_lo] ----------
__global__ void convert_fused(const u32x4* __restrict__ w4,
                              u16x8* __restrict__ s8,
                              const f4* __restrict__ x4,
                              uint16_t* __restrict__ Ab, int n8) {
  const int half = 2048;
  if (blockIdx.x < half) {  // W path: 32B in -> 16B out
    int idx = blockIdx.x * 256 + threadIdx.x;
    int stride = half * 256;
    for (int i = idx; i < n8; i += stride) {
      u32x4 a = w4[2 * i], b = w4[2 * i + 1];
      u16x8 o;
#pragma unroll
      for (int j = 0; j < 4; ++j) {
        uint32_t ua = a[j], ub = b[j];
        o[j] = ((ua & 0x7fffffffu) == 0u)
                   ? (uint16_t)0
                   : (uint16_t)(0x3F80u | ((ua >> 16) & 0x8000u));
        o[4 + j] = ((ub & 0x7fffffffu) == 0u)
                       ? (uint16_t)0
                       : (uint16_t)(0x3F80u | ((ub >> 16) & 0x8000u));
      }
      s8[i] = o;
    }
  } else {  // X path: 32B in -> 2x 16B out (hi row-half, lo row-half)
    int idx = (blockIdx.x - half) * 256 + threadIdx.x;
    int stride = half * 256;
    for (int i = idx; i < n8; i += stride) {
      f4 a = x4[2 * i], b = x4[2 * i + 1];
      u16x8 h, l;
#pragma unroll
      for (int j = 0; j < 4; ++j) {
        uint16_t hb = f32_to_bf16_rn(a[j]);
        h[j] = hb;
        l[j] = f32_to_bf16_rn(a[j] - __uint_as_float((uint32_t)hb << 16));
        uint16_t hb2 = f32_to_bf16_rn(b[j]);
        h[4 + j] = hb2;
        l[4 + j] = f32_to_bf16_rn(b[j] - __uint_as_float((uint32_t)hb2 << 16));
      }
      int flat = i * 8;
      int m = flat >> 12;   // / 4096
      int k = flat & 4095;  // 8-aligned
      *(u16x8*)&Ab[(size_t)m * 8192 + k] = h;
      *(u16x8*)&Ab[(size_t)m * 8192 + 4096 + k] = l;
    }
  }
}

__device__ __forceinline__ void gload_lds16(const void* g, void* l) {
  __builtin_amdgcn_global_load_lds(
      (__attribute__((address_space(1))) void*)(g),
      (__attribute__((address_space(3))) void*)(l),
      16, 0, 0);
}

// ---------------- 256x256 8-phase GEMM with B-reuse ----------------
// A': [4096][8192] bf16 (hi cols 0-4095 | lo 4096-8191). B: sign(W) [N][K].
// Per orig K-tile: p1-p4 consume A_hi + B (B frags -> regs), p5-p8 consume
// A_lo reusing B regs. sAh/sAl single-buffered, sB double-buffered = 128KB.
__global__ __launch_bounds__(512, 2)
void bingemm8(const uint16_t* __restrict__ Ab, const uint16_t* __restrict__ Bs,
              const float* __restrict__ bias, float* __restrict__ out) {
  __shared__ uint16_t sAh[2][8192];     // [half: rows 0-127 / 128-255][128x64]
  __shared__ uint16_t sAl[2][8192];
  __shared__ uint16_t sB[2][2][8192];   // [dbuf][half]

  const int t = threadIdx.x;
  const int lane = t & 63;
  const int w = t >> 6;
  const int r15 = lane & 15;

  // XCD-aware bijective swizzle: 256 blocks, 32 per XCD
  const int bid = blockIdx.x;
  const int swz = (bid & 7) * 32 + (bid >> 3);
  const int bm = (swz >> 4) * 256;
  const int bn = (swz & 15) * 256;

  // staging: inverse-swizzled global source, linear LDS dest
  const int srow = t >> 3;
  const int scol = (((t & 7) ^ (srow & 7)) * 8);
  const size_t aThr = (size_t)(bm + srow) * 8192 + scol;
  const size_t bThr = (size_t)(bn + srow) * 4096 + scol;

#define STAGE_AH(KT, HH)                                            \
  do {                                                              \
    const uint16_t* g = Ab + aThr + (size_t)(HH) * 128 * 8192 +     \
                        (size_t)(KT) * 64;                          \
    gload_lds16(g, &sAh[HH][t * 8]);                                \
    gload_lds16(g + (size_t)64 * 8192, &sAh[HH][t * 8 + 4096]);     \
  } while (0)
#define STAGE_AL(KT, HH)                                            \
  do {                                                              \
    const uint16_t* g = Ab + aThr + (size_t)(HH) * 128 * 8192 +     \
                        4096 + (size_t)(KT) * 64;                   \
    gload_lds16(g, &sAl[HH][t * 8]);                                \
    gload_lds16(g + (size_t)64 * 8192, &sAl[HH][t * 8 + 4096]);     \
  } while (0)
#define STAGE_B(KT, HH, BUF)                                        \
  do {                                                              \
    const uint16_t* g = Bs + bThr + (size_t)(HH) * 128 * 4096 +     \
                        (size_t)(KT) * 64;                          \
    gload_lds16(g, &sB[BUF][HH][t * 8]);                            \
    gload_lds16(g + (size_t)64 * 4096, &sB[BUF][HH][t * 8 + 4096]); \
  } while (0)

  // fragment-read addressing (swizzled; read chunk = desired ^ (row&7))
  const int klane = lane >> 4;
  const int cb0 = (klane * 16) ^ ((lane & 7) << 4);
  const int whA = w >> 2;
  const int whB = (w & 3) >> 1;
  const int wcl = (w & 1) * 64;
  const int eA0 = r15 * 64 + (cb0 >> 1);
  const int eA1 = eA0 ^ 32;
  const int eB0 = (wcl + r15) * 64 + (cb0 >> 1);
  const int eB1 = eB0 ^ 32;

  bf16x8 rAa[4], rAb[4], rBa[4], rBb[4];
  f32x4 acc[8][4];
#pragma unroll
  for (int m = 0; m < 8; ++m)
#pragma unroll
    for (int n = 0; n < 4; ++n) acc[m][n] = (f32x4){0.f, 0.f, 0.f, 0.f};

#define LOAD_A0(SRC, MOFF)                                                  \
  {                                                                         \
    _Pragma("unroll") for (int m = 0; m < 4; ++m)                           \
        rAa[m] = *(const bf16x8*)&SRC[whA][eA0 + ((MOFF) + m) * 1024];      \
  }
#define LOAD_A1(SRC, MOFF)                                                  \
  {                                                                         \
    _Pragma("unroll") for (int m = 0; m < 4; ++m)                           \
        rAb[m] = *(const bf16x8*)&SRC[whA][eA1 + ((MOFF) + m) * 1024];      \
  }
#define LOAD_B0(BUF)                                                        \
  {                                                                         \
    _Pragma("unroll") for (int n = 0; n < 4; ++n)                           \
        rBa[n] = *(const bf16x8*)&sB[BUF][whB][eB0 + n * 1024];             \
  }
#define LOAD_B1(BUF)                                                        \
  {                                                                         \
    _Pragma("unroll") for (int n = 0; n < 4; ++n)                           \
        rBb[n] = *(const bf16x8*)&sB[BUF][whB][eB1 + n * 1024];             \
  }
#define MFMA16(MB, RA, RB)                                                  \
  {                                                                         \
    _Pragma("unroll") for (int mm = 0; mm < 4; ++mm)                        \
    _Pragma("unroll") for (int nn = 0; nn < 4; ++nn)                        \
        acc[(MB) + mm][nn] = __builtin_amdgcn_mfma_f32_16x16x32_bf16(       \
            RA[mm], RB[nn], acc[(MB) + mm][nn], 0, 0, 0);                   \
  }
#define PH_PRE()                                        \
  __builtin_amdgcn_s_barrier();                         \
  asm volatile("s_waitcnt lgkmcnt(0)" ::: "memory");    \
  __builtin_amdgcn_sched_barrier(0);                    \
  __builtin_amdgcn_s_setprio(1);
#define PH_POST()                                       \
  __builtin_amdgcn_s_setprio(0);                        \
  __builtin_amdgcn_s_barrier();
#define PH_POST_VM4()                                   \
  __builtin_amdgcn_s_setprio(0);                        \
  asm volatile("s_waitcnt vmcnt(4)" ::: "memory");      \
  __builtin_amdgcn_s_barrier();
#define PH_POST_VM0()                                   \
  __builtin_amdgcn_s_setprio(0);                        \
  asm volatile("s_waitcnt vmcnt(0)" ::: "memory");      \
  __builtin_amdgcn_s_barrier();

  // one orig-K-tile: 8 phases. Stage rotation (re-derived, race-screened):
  //  p1/p2: AL(kt)   -> sAl    (read p5-p8; confirmed p4 vmcnt(4))
  //  p3/p4: B(kt+1)  -> sB[b^1] (dbuf; confirmed p8 vmcnt(0))
  //  p5/p6: AH(kt+1) -> sAh    (sAh last read p4; confirmed p8 vmcnt(0))
#define TILE_BODY(KT)                                           \
  {                                                             \
    const int b = (KT) & 1;                                     \
    const int bn1 = b ^ 1;                                      \
    const int kp1 = ((KT) + 1 < NTO) ? ((KT) + 1) : (NTO - 1);  \
    LOAD_A0(sAh, 0);                                            \
    LOAD_B0(b);                                                 \
    STAGE_AL(KT, 0);                                            \
    PH_PRE();                                                   \
    MFMA16(0, rAa, rBa);                                        \
    PH_POST();                                                  \
    LOAD_A1(sAh, 0);                                            \
    LOAD_B1(b);                                                 \
    STAGE_AL(KT, 1);                                            \
    PH_PRE();                                                   \
    MFMA16(0, rAb, rBb);                                        \
    PH_POST();                                                  \
    LOAD_A0(sAh, 4);                                            \
    STAGE_B(kp1, 0, bn1);                                       \
    PH_PRE();                                                   \
    MFMA16(4, rAa, rBa);                                        \
    PH_POST();                                                  \
    LOAD_A1(sAh, 4);                                            \
    STAGE_B(kp1, 1, bn1);                                       \
    PH_PRE();                                                   \
    MFMA16(4, rAb, rBb);                                        \
    PH_POST_VM4();                                              \
    LOAD_A0(sAl, 0);                                            \
    STAGE_AH(kp1, 0);                                           \
    PH_PRE();                                                   \
    MFMA16(0, rAa, rBa);                                        \
    PH_POST();                                                  \
    LOAD_A1(sAl, 0);                                            \
    STAGE_AH(kp1, 1);                                           \
    PH_PRE();                                                   \
    MFMA16(0, rAb, rBb);                                        \
    PH_POST();                                                  \
    LOAD_A0(sAl, 4);                                            \
    PH_PRE();                                                   \
    MFMA16(4, rAa, rBa);                                        \
    PH_POST();                                                  \
    LOAD_A1(sAl, 4);                                            \
    PH_PRE();                                                   \
    MFMA16(4, rAb, rBb);                                        \
    PH_POST_VM0();                                              \
  }

  // prologue: AH(0) + B(0) into sB[0]; AL(0) staged in-loop at p1/p2
  STAGE_AH(0, 0);
  STAGE_AH(0, 1);
  STAGE_B(0, 0, 0);
  STAGE_B(0, 1, 0);
  asm volatile("s_waitcnt vmcnt(0)" ::: "memory");
  __builtin_amdgcn_s_barrier();

  for (int i2 = 0; i2 < NTO / 2; ++i2) {
    TILE_BODY(2 * i2);
    TILE_BODY(2 * i2 + 1);
  }

  asm volatile("s_waitcnt vmcnt(0)" ::: "memory");

  // epilogue: C/D layout col=lane&15, row=(lane>>4)*4+reg [m89/m91]
  const int rowg = (lane >> 4) * 4;
#pragma unroll
  for (int n = 0; n < 4; ++n) {
    const int col = bn + (w & 3) * 64 + n * 16 + r15;
    const float bv = bias[col];
#pragma unroll
    for (int m = 0; m < 8; ++m) {
      const int row0 = bm + (w >> 2) * 128 + m * 16 + rowg;
#pragma unroll
      for (int k = 0; k < 4; ++k)
        out[(size_t)(row0 + k) * N_DIM + col] = acc[m][n][k] + bv;
    }
  }
}

// ---------- fallback (workspace too small): fp32 tiled ----------
__global__ void fallback_gemm(const float* __restrict__ x,
                              const float* __restrict__ w,
                              const float* __restrict__ bias,
                              float* __restrict__ out) {
  __shared__ float sx[16][17];
  __shared__ float sw[16][17];
  int tx = threadIdx.x & 15, ty = threadIdx.x >> 4;
  int m = blockIdx.y * 16 + ty;
  int n = blockIdx.x * 16 + tx;
  float acc = 0.f;
  for (int k0 = 0; k0 < K_DIM; k0 += 16) {
    sx[ty][tx] = x[(size_t)m * K_DIM + k0 + tx];
    float wv = w[(size_t)(blockIdx.x * 16 + ty) * K_DIM + k0 + tx];
    sw[ty][tx] = (wv > 0.f) ? 1.f : ((wv < 0.f) ? -1.f : 0.f);
    __syncthreads();
#pragma unroll
    for (int kk = 0; kk < 16; ++kk) acc += sx[ty][kk] * sw[tx][kk];
    __syncthreads();
  }
  out[(size_t)m * N_DIM + n] = acc + bias[n];
}

extern "C" void kernel_launch(void* const* d_in, const int* in_sizes, int n_in,
                              void* d_out, int out_size, void* d_ws,
                              size_t ws_size, hipStream_t stream) {
  const float* x = (const float*)d_in[0];
  const float* w = (const float*)d_in[1];
  const float* bias = (const float*)d_in[2];
  float* out = (float*)d_out;

  const size_t elems = (size_t)N_DIM * K_DIM;
  const size_t need = elems * 2u * 3u;  // Sb + A'(hi|lo) bf16 = 96 MiB

  if (ws_size < need) {
    dim3 grid(N_DIM / 16, M_DIM / 16);
    fallback_gemm<<<grid, 256, 0, stream>>>(x, w, bias, out);
    return;
  }

  uint16_t* Sb = (uint16_t*)d_ws;  // [4096][4096] sign(W) bf16
  uint16_t* Ab = Sb + elems;       // [4096][8192] (x_hi | x_lo) bf16

  const int n8 = (int)(elems / 8);
  convert_fused<<<4096, 256, 0, stream>>>((const u32x4*)w, (u16x8*)Sb,
                                          (const f4*)x, Ab, n8);

  bingemm8<<<dim3(256), 512, 0, stream>>>(Ab, Sb, bias, out);
}

// Round 10
// 378.566 us; speedup vs baseline: 1.0305x; 1.0305x over previous
//
#include <hip/hip_runtime.h>
#include <hip/hip_bf16.h>
#include <stdint.h>

#define M_DIM 4096
#define N_DIM 4096
#define K_DIM 4096
#define NTO 64  // orig K-tiles of 64

typedef float f32x4 __attribute__((ext_vector_type(4)));
typedef __bf16 bf16x8 __attribute__((ext_vector_type(8)));
typedef float f4 __attribute__((ext_vector_type(4)));
typedef unsigned int u32x4 __attribute__((ext_vector_type(4)));
typedef unsigned short u16x8 __attribute__((ext_vector_type(8)));

__device__ __forceinline__ uint16_t f32_to_bf16_rn(float f) {
  uint32_t u = __float_as_uint(f);
  u += 0x7fffu + ((u >> 16) & 1u);
  return (uint16_t)(u >> 16);
}

// ---------- fused: W -> sign(W) bf16 ; x -> A' = [x_hi | x_lo] ----------
__global__ void convert_fused(const u32x4* __restrict__ w4,
                              u16x8* __restrict__ s8,
                              const f4* __restrict__ x4,
                              uint16_t* __restrict__ Ab, int n8) {
  const int half = 2048;
  if (blockIdx.x < half) {  // W path: 32B in -> 16B out
    int idx = blockIdx.x * 256 + threadIdx.x;
    int stride = half * 256;
    for (int i = idx; i < n8; i += stride) {
      u32x4 a = w4[2 * i], b = w4[2 * i + 1];
      u16x8 o;
#pragma unroll
      for (int j = 0; j < 4; ++j) {
        uint32_t ua = a[j], ub = b[j];
        o[j] = ((ua & 0x7fffffffu) == 0u)
                   ? (uint16_t)0
                   : (uint16_t)(0x3F80u | ((ua >> 16) & 0x8000u));
        o[4 + j] = ((ub & 0x7fffffffu) == 0u)
                       ? (uint16_t)0
                       : (uint16_t)(0x3F80u | ((ub >> 16) & 0x8000u));
      }
      s8[i] = o;
    }
  } else {  // X path: 32B in -> 2x 16B out (hi row-half, lo row-half)
    int idx = (blockIdx.x - half) * 256 + threadIdx.x;
    int stride = half * 256;
    for (int i = idx; i < n8; i += stride) {
      f4 a = x4[2 * i], b = x4[2 * i + 1];
      u16x8 h, l;
#pragma unroll
      for (int j = 0; j < 4; ++j) {
        uint16_t hb = f32_to_bf16_rn(a[j]);
        h[j] = hb;
        l[j] = f32_to_bf16_rn(a[j] - __uint_as_float((uint32_t)hb << 16));
        uint16_t hb2 = f32_to_bf16_rn(b[j]);
        h[4 + j] = hb2;
        l[4 + j] = f32_to_bf16_rn(b[j] - __uint_as_float((uint32_t)hb2 << 16));
      }
      int flat = i * 8;
      int m = flat >> 12;   // / 4096
      int k = flat & 4095;  // 8-aligned
      *(u16x8*)&Ab[(size_t)m * 8192 + k] = h;
      *(u16x8*)&Ab[(size_t)m * 8192 + 4096 + k] = l;
    }
  }
}

__device__ __forceinline__ void gload_lds16(const void* g, void* l) {
  __builtin_amdgcn_global_load_lds(
      (__attribute__((address_space(1))) void*)(g),
      (__attribute__((address_space(3))) void*)(l),
      16, 0, 0);
}

// ---------------- 256x256 4-fat-phase GEMM with B-reuse ----------------
// A': [4096][8192] bf16 (hi cols 0-4095 | lo 4096-8191). B: sign(W) [N][K].
// Per orig K-tile: 4 phases x 32 MFMA. B frags load once (P1) and stay in
// regs for all 4 phases. sAh/sAl single-buffered, sB double-buffered = 128KB.
__global__ __launch_bounds__(512, 2)
void bingemm8(const uint16_t* __restrict__ Ab, const uint16_t* __restrict__ Bs,
              const float* __restrict__ bias, float* __restrict__ out) {
  __shared__ uint16_t sAh[2][8192];     // [half: rows 0-127 / 128-255][128x64]
  __shared__ uint16_t sAl[2][8192];
  __shared__ uint16_t sB[2][2][8192];   // [dbuf][half]

  const int t = threadIdx.x;
  const int lane = t & 63;
  const int w = t >> 6;
  const int r15 = lane & 15;

  // XCD-aware bijective swizzle: 256 blocks, 32 per XCD
  const int bid = blockIdx.x;
  const int swz = (bid & 7) * 32 + (bid >> 3);
  const int bm = (swz >> 4) * 256;
  const int bn = (swz & 15) * 256;

  // staging: inverse-swizzled global source, linear LDS dest
  const int srow = t >> 3;
  const int scol = (((t & 7) ^ (srow & 7)) * 8);
  const size_t aThr = (size_t)(bm + srow) * 8192 + scol;
  const size_t bThr = (size_t)(bn + srow) * 4096 + scol;

#define STAGE_AH(KT, HH)                                            \
  do {                                                              \
    const uint16_t* g = Ab + aThr + (size_t)(HH) * 128 * 8192 +     \
                        (size_t)(KT) * 64;                          \
    gload_lds16(g, &sAh[HH][t * 8]);                                \
    gload_lds16(g + (size_t)64 * 8192, &sAh[HH][t * 8 + 4096]);     \
  } while (0)
#define STAGE_AL(KT, HH)                                            \
  do {                                                              \
    const uint16_t* g = Ab + aThr + (size_t)(HH) * 128 * 8192 +     \
                        4096 + (size_t)(KT) * 64;                   \
    gload_lds16(g, &sAl[HH][t * 8]);                                \
    gload_lds16(g + (size_t)64 * 8192, &sAl[HH][t * 8 + 4096]);     \
  } while (0)
#define STAGE_B(KT, HH, BUF)                                        \
  do {                                                              \
    const uint16_t* g = Bs + bThr + (size_t)(HH) * 128 * 4096 +     \
                        (size_t)(KT) * 64;                          \
    gload_lds16(g, &sB[BUF][HH][t * 8]);                            \
    gload_lds16(g + (size_t)64 * 4096, &sB[BUF][HH][t * 8 + 4096]); \
  } while (0)

  // fragment-read addressing (swizzled; read chunk = desired ^ (row&7))
  const int klane = lane >> 4;
  const int cb0 = (klane * 16) ^ ((lane & 7) << 4);
  const int whA = w >> 2;
  const int whB = (w & 3) >> 1;
  const int wcl = (w & 1) * 64;
  const int eA0 = r15 * 64 + (cb0 >> 1);
  const int eA1 = eA0 ^ 32;
  const int eB0 = (wcl + r15) * 64 + (cb0 >> 1);
  const int eB1 = eB0 ^ 32;

  bf16x8 rAa[4], rAb[4], rBa[4], rBb[4];
  f32x4 acc[8][4];
#pragma unroll
  for (int m = 0; m < 8; ++m)
#pragma unroll
    for (int n = 0; n < 4; ++n) acc[m][n] = (f32x4){0.f, 0.f, 0.f, 0.f};

#define LOAD_A0(SRC, MOFF)                                                  \
  {                                                                         \
    _Pragma("unroll") for (int m = 0; m < 4; ++m)                           \
        rAa[m] = *(const bf16x8*)&SRC[whA][eA0 + ((MOFF) + m) * 1024];      \
  }
#define LOAD_A1(SRC, MOFF)                                                  \
  {                                                                         \
    _Pragma("unroll") for (int m = 0; m < 4; ++m)                           \
        rAb[m] = *(const bf16x8*)&SRC[whA][eA1 + ((MOFF) + m) * 1024];      \
  }
#define LOAD_B0(BUF)                                                        \
  {                                                                         \
    _Pragma("unroll") for (int n = 0; n < 4; ++n)                           \
        rBa[n] = *(const bf16x8*)&sB[BUF][whB][eB0 + n * 1024];             \
  }
#define LOAD_B1(BUF)                                                        \
  {                                                                         \
    _Pragma("unroll") for (int n = 0; n < 4; ++n)                           \
        rBb[n] = *(const bf16x8*)&sB[BUF][whB][eB1 + n * 1024];             \
  }
  // 32 independent MFMAs: rows (MB..MB+3) x 4 col-tiles x both k-slices
#define MFMA32(MB)                                                          \
  {                                                                         \
    _Pragma("unroll") for (int mm = 0; mm < 4; ++mm)                        \
    _Pragma("unroll") for (int nn = 0; nn < 4; ++nn) {                      \
      acc[(MB) + mm][nn] = __builtin_amdgcn_mfma_f32_16x16x32_bf16(         \
          rAa[mm], rBa[nn], acc[(MB) + mm][nn], 0, 0, 0);                   \
      acc[(MB) + mm][nn] = __builtin_amdgcn_mfma_f32_16x16x32_bf16(         \
          rAb[mm], rBb[nn], acc[(MB) + mm][nn], 0, 0, 0);                   \
    }                                                                       \
  }
#define PH_PRE()                                        \
  __builtin_amdgcn_s_barrier();                         \
  asm volatile("s_waitcnt lgkmcnt(0)" ::: "memory");    \
  __builtin_amdgcn_sched_barrier(0);                    \
  __builtin_amdgcn_s_setprio(1);
#define PH_POST()                                       \
  __builtin_amdgcn_s_setprio(0);                        \
  __builtin_amdgcn_s_barrier();
#define PH_POST_VM4()                                   \
  __builtin_amdgcn_s_setprio(0);                        \
  asm volatile("s_waitcnt vmcnt(4)" ::: "memory");      \
  __builtin_amdgcn_s_barrier();
#define PH_POST_VM0()                                   \
  __builtin_amdgcn_s_setprio(0);                        \
  asm volatile("s_waitcnt vmcnt(0)" ::: "memory");      \
  __builtin_amdgcn_s_barrier();

  // one orig-K-tile: 4 fat phases (32 MFMA each). Stage rotation:
  //  P1: AL(kt)  -> sAl   (read P3/P4; confirmed end-P2 vmcnt(4))
  //  P2: B(kt+1) -> sB[b^1] (last read: prev tile P1 — 7 barriers gap)
  //  P3: AH(kt+1)-> sAh   (sAh last read P2 shadow; gap = P2 POST barrier)
  //  end-P4 vmcnt(0): B(kt+1)+AH(kt+1) landed before next-P1 reads them.
#define TILE_BODY(KT)                                           \
  {                                                             \
    const int b = (KT) & 1;                                     \
    const int bn1 = b ^ 1;                                      \
    const int kp1 = ((KT) + 1 < NTO) ? ((KT) + 1) : (NTO - 1);  \
    /* P1: hi rows 0-3, both ks */                              \
    LOAD_A0(sAh, 0);                                            \
    LOAD_A1(sAh, 0);                                            \
    LOAD_B0(b);                                                 \
    LOAD_B1(b);                                                 \
    STAGE_AL(KT, 0);                                            \
    STAGE_AL(KT, 1);                                            \
    PH_PRE();                                                   \
    MFMA32(0);                                                  \
    PH_POST();                                                  \
    /* P2: hi rows 4-7 */                                       \
    LOAD_A0(sAh, 4);                                            \
    LOAD_A1(sAh, 4);                                            \
    STAGE_B(kp1, 0, bn1);                                       \
    STAGE_B(kp1, 1, bn1);                                       \
    PH_PRE();                                                   \
    MFMA32(4);                                                  \
    PH_POST_VM4();                                              \
    /* P3: lo rows 0-3 (B regs reused) */                       \
    LOAD_A0(sAl, 0);                                            \
    LOAD_A1(sAl, 0);                                            \
    STAGE_AH(kp1, 0);                                           \
    STAGE_AH(kp1, 1);                                           \
    PH_PRE();                                                   \
    MFMA32(0);                                                  \
    PH_POST();                                                  \
    /* P4: lo rows 4-7 */                                       \
    LOAD_A0(sAl, 4);                                            \
    LOAD_A1(sAl, 4);                                            \
    PH_PRE();                                                   \
    MFMA32(4);                                                  \
    PH_POST_VM0();                                              \
  }

  // prologue: AH(0) + B(0) into sB[0]; AL(0) staged in-loop at P1
  STAGE_AH(0, 0);
  STAGE_AH(0, 1);
  STAGE_B(0, 0, 0);
  STAGE_B(0, 1, 0);
  asm volatile("s_waitcnt vmcnt(0)" ::: "memory");
  __builtin_amdgcn_s_barrier();

  for (int i2 = 0; i2 < NTO / 2; ++i2) {
    TILE_BODY(2 * i2);
    TILE_BODY(2 * i2 + 1);
  }

  asm volatile("s_waitcnt vmcnt(0)" ::: "memory");

  // epilogue: C/D layout col=lane&15, row=(lane>>4)*4+reg [m89/m91]
  const int rowg = (lane >> 4) * 4;
#pragma unroll
  for (int n = 0; n < 4; ++n) {
    const int col = bn + (w & 3) * 64 + n * 16 + r15;
    const float bv = bias[col];
#pragma unroll
    for (int m = 0; m < 8; ++m) {
      const int row0 = bm + (w >> 2) * 128 + m * 16 + rowg;
#pragma unroll
      for (int k = 0; k < 4; ++k)
        out[(size_t)(row0 + k) * N_DIM + col] = acc[m][n][k] + bv;
    }
  }
}

// ---------- fallback (workspace too small): fp32 tiled ----------
__global__ void fallback_gemm(const float* __restrict__ x,
                              const float* __restrict__ w,
                              const float* __restrict__ bias,
                              float* __restrict__ out) {
  __shared__ float sx[16][17];
  __shared__ float sw[16][17];
  int tx = threadIdx.x & 15, ty = threadIdx.x >> 4;
  int m = blockIdx.y * 16 + ty;
  int n = blockIdx.x * 16 + tx;
  float acc = 0.f;
  for (int k0 = 0; k0 < K_DIM; k0 += 16) {
    sx[ty][tx] = x[(size_t)m * K_DIM + k0 + tx];
    float wv = w[(size_t)(blockIdx.x * 16 + ty) * K_DIM + k0 + tx];
    sw[ty][tx] = (wv > 0.f) ? 1.f : ((wv < 0.f) ? -1.f : 0.f);
    __syncthreads();
#pragma unroll
    for (int kk = 0; kk < 16; ++kk) acc += sx[ty][kk] * sw[tx][kk];
    __syncthreads();
  }
  out[(size_t)m * N_DIM + n] = acc + bias[n];
}

extern "C" void kernel_launch(void* const* d_in, const int* in_sizes, int n_in,
                              void* d_out, int out_size, void* d_ws,
                              size_t ws_size, hipStream_t stream) {
  const float* x = (const float*)d_in[0];
  const float* w = (const float*)d_in[1];
  const float* bias = (const float*)d_in[2];
  float* out = (float*)d_out;

  const size_t elems = (size_t)N_DIM * K_DIM;
  const size_t need = elems * 2u * 3u;  // Sb + A'(hi|lo) bf16 = 96 MiB

  if (ws_size < need) {
    dim3 grid(N_DIM / 16, M_DIM / 16);
    fallback_gemm<<<grid, 256, 0, stream>>>(x, w, bias, out);
    return;
  }

  uint16_t* Sb = (uint16_t*)d_ws;  // [4096][4096] sign(W) bf16
  uint16_t* Ab = Sb + elems;       // [4096][8192] (x_hi | x_lo) bf16

  const int n8 = (int)(elems / 8);
  convert_fused<<<4096, 256, 0, stream>>>((const u32x4*)w, (u16x8*)Sb,
                                          (const f4*)x, Ab, n8);

  bingemm8<<<dim3(256), 512, 0, stream>>>(Ab, Sb, bias, out);
}

// Round 11
// 370.737 us; speedup vs baseline: 1.0523x; 1.0211x over previous
//
#include <hip/hip_runtime.h>
#include <hip/hip_bf16.h>
#include <stdint.h>

#define M_DIM 4096
#define N_DIM 4096
#define K_DIM 4096
#define NTO 64  // orig K-tiles of 64

typedef float f32x4 __attribute__((ext_vector_type(4)));
typedef __bf16 bf16x8 __attribute__((ext_vector_type(8)));
typedef float f4 __attribute__((ext_vector_type(4)));
typedef unsigned int u32x4 __attribute__((ext_vector_type(4)));
typedef unsigned short u16x8 __attribute__((ext_vector_type(8)));

__device__ __forceinline__ uint16_t f32_to_bf16_rn(float f) {
  uint32_t u = __float_as_uint(f);
  u += 0x7fffu + ((u >> 16) & 1u);
  return (uint16_t)(u >> 16);
}

// ---------- fused: W -> sign(W) bf16 ; x -> A' = [x_hi | x_lo] ----------
__global__ void convert_fused(const u32x4* __restrict__ w4,
                              u16x8* __restrict__ s8,
                              const f4* __restrict__ x4,
                              uint16_t* __restrict__ Ab, int n8) {
  const int half = 2048;
  if (blockIdx.x < half) {  // W path: 32B in -> 16B out
    int idx = blockIdx.x * 256 + threadIdx.x;
    int stride = half * 256;
    for (int i = idx; i < n8; i += stride) {
      u32x4 a = w4[2 * i], b = w4[2 * i + 1];
      u16x8 o;
#pragma unroll
      for (int j = 0; j < 4; ++j) {
        uint32_t ua = a[j], ub = b[j];
        o[j] = ((ua & 0x7fffffffu) == 0u)
                   ? (uint16_t)0
                   : (uint16_t)(0x3F80u | ((ua >> 16) & 0x8000u));
        o[4 + j] = ((ub & 0x7fffffffu) == 0u)
                       ? (uint16_t)0
                       : (uint16_t)(0x3F80u | ((ub >> 16) & 0x8000u));
      }
      s8[i] = o;
    }
  } else {  // X path: 32B in -> 2x 16B out (hi row-half, lo row-half)
    int idx = (blockIdx.x - half) * 256 + threadIdx.x;
    int stride = half * 256;
    for (int i = idx; i < n8; i += stride) {
      f4 a = x4[2 * i], b = x4[2 * i + 1];
      u16x8 h, l;
#pragma unroll
      for (int j = 0; j < 4; ++j) {
        uint16_t hb = f32_to_bf16_rn(a[j]);
        h[j] = hb;
        l[j] = f32_to_bf16_rn(a[j] - __uint_as_float((uint32_t)hb << 16));
        uint16_t hb2 = f32_to_bf16_rn(b[j]);
        h[4 + j] = hb2;
        l[4 + j] = f32_to_bf16_rn(b[j] - __uint_as_float((uint32_t)hb2 << 16));
      }
      int flat = i * 8;
      int m = flat >> 12;   // / 4096
      int k = flat & 4095;  // 8-aligned
      *(u16x8*)&Ab[(size_t)m * 8192 + k] = h;
      *(u16x8*)&Ab[(size_t)m * 8192 + 4096 + k] = l;
    }
  }
}

__device__ __forceinline__ void gload_lds16(const void* g, void* l) {
  __builtin_amdgcn_global_load_lds(
      (__attribute__((address_space(1))) void*)(g),
      (__attribute__((address_space(3))) void*)(l),
      16, 0, 0);
}

// ------------- 256x256 GEMM, B-reuse, de-lockstepped halves -------------
// A': [4096][8192] bf16 (hi cols 0-4095 | lo 4096-8191). B: sign(W) [N][K].
// Per orig K-tile: 2 barrier-bounded halves (hi, lo), each with 2
// read+MFMA segments separated only by lgkmcnt(0)+sched_barrier — waves on
// a SIMD drift anti-phase so LDS reads overlap MFMA (breaks the measured
// LDS+MFMA serialization: 8848 = 4966 MFMA + 3840 LDS cyc/tile lockstep).
__global__ __launch_bounds__(512, 2)
void bingemm8(const uint16_t* __restrict__ Ab, const uint16_t* __restrict__ Bs,
              const float* __restrict__ bias, float* __restrict__ out) {
  __shared__ uint16_t sAh[2][8192];     // [half: rows 0-127 / 128-255][128x64]
  __shared__ uint16_t sAl[2][8192];
  __shared__ uint16_t sB[2][2][8192];   // [dbuf][half]

  const int t = threadIdx.x;
  const int lane = t & 63;
  const int w = t >> 6;
  const int r15 = lane & 15;

  // XCD-aware bijective swizzle: 256 blocks, 32 per XCD
  const int bid = blockIdx.x;
  const int swz = (bid & 7) * 32 + (bid >> 3);
  const int bm = (swz >> 4) * 256;
  const int bn = (swz & 15) * 256;

  // staging: inverse-swizzled global source, linear LDS dest
  const int srow = t >> 3;
  const int scol = (((t & 7) ^ (srow & 7)) * 8);
  const size_t aThr = (size_t)(bm + srow) * 8192 + scol;
  const size_t bThr = (size_t)(bn + srow) * 4096 + scol;

#define STAGE_AH(KT, HH)                                            \
  do {                                                              \
    const uint16_t* g = Ab + aThr + (size_t)(HH) * 128 * 8192 +     \
                        (size_t)(KT) * 64;                          \
    gload_lds16(g, &sAh[HH][t * 8]);                                \
    gload_lds16(g + (size_t)64 * 8192, &sAh[HH][t * 8 + 4096]);     \
  } while (0)
#define STAGE_AL(KT, HH)                                            \
  do {                                                              \
    const uint16_t* g = Ab + aThr + (size_t)(HH) * 128 * 8192 +     \
                        4096 + (size_t)(KT) * 64;                   \
    gload_lds16(g, &sAl[HH][t * 8]);                                \
    gload_lds16(g + (size_t)64 * 8192, &sAl[HH][t * 8 + 4096]);     \
  } while (0)
#define STAGE_B(KT, HH, BUF)                                        \
  do {                                                              \
    const uint16_t* g = Bs + bThr + (size_t)(HH) * 128 * 4096 +     \
                        (size_t)(KT) * 64;                          \
    gload_lds16(g, &sB[BUF][HH][t * 8]);                            \
    gload_lds16(g + (size_t)64 * 4096, &sB[BUF][HH][t * 8 + 4096]); \
  } while (0)

  // fragment-read addressing (swizzled; read chunk = desired ^ (row&7))
  const int klane = lane >> 4;
  const int cb0 = (klane * 16) ^ ((lane & 7) << 4);
  const int whA = w >> 2;
  const int whB = (w & 3) >> 1;
  const int wcl = (w & 1) * 64;
  const int eA0 = r15 * 64 + (cb0 >> 1);
  const int eA1 = eA0 ^ 32;
  const int eB0 = (wcl + r15) * 64 + (cb0 >> 1);
  const int eB1 = eB0 ^ 32;

  bf16x8 rAa[4], rAb[4], rBa[4], rBb[4];
  f32x4 acc[8][4];
#pragma unroll
  for (int m = 0; m < 8; ++m)
#pragma unroll
    for (int n = 0; n < 4; ++n) acc[m][n] = (f32x4){0.f, 0.f, 0.f, 0.f};

#define LOAD_A0(SRC, MOFF)                                                  \
  {                                                                         \
    _Pragma("unroll") for (int m = 0; m < 4; ++m)                           \
        rAa[m] = *(const bf16x8*)&SRC[whA][eA0 + ((MOFF) + m) * 1024];      \
  }
#define LOAD_A1(SRC, MOFF)                                                  \
  {                                                                         \
    _Pragma("unroll") for (int m = 0; m < 4; ++m)                           \
        rAb[m] = *(const bf16x8*)&SRC[whA][eA1 + ((MOFF) + m) * 1024];      \
  }
#define LOAD_B0(BUF)                                                        \
  {                                                                         \
    _Pragma("unroll") for (int n = 0; n < 4; ++n)                           \
        rBa[n] = *(const bf16x8*)&sB[BUF][whB][eB0 + n * 1024];             \
  }
#define LOAD_B1(BUF)                                                        \
  {                                                                         \
    _Pragma("unroll") for (int n = 0; n < 4; ++n)                           \
        rBb[n] = *(const bf16x8*)&sB[BUF][whB][eB1 + n * 1024];             \
  }
  // 32 independent MFMAs: rows (MB..MB+3) x 4 col-tiles x both k-slices
#define MFMA32(MB)                                                          \
  {                                                                         \
    _Pragma("unroll") for (int mm = 0; mm < 4; ++mm)                        \
    _Pragma("unroll") for (int nn = 0; nn < 4; ++nn) {                      \
      acc[(MB) + mm][nn] = __builtin_amdgcn_mfma_f32_16x16x32_bf16(         \
          rAa[mm], rBa[nn], acc[(MB) + mm][nn], 0, 0, 0);                   \
      acc[(MB) + mm][nn] = __builtin_amdgcn_mfma_f32_16x16x32_bf16(         \
          rAb[mm], rBb[nn], acc[(MB) + mm][nn], 0, 0, 0);                   \
    }                                                                       \
  }
  // per-wave segment boundary: own reads done, then MFMA (NO barrier)
#define WAITK()                                         \
  asm volatile("s_waitcnt lgkmcnt(0)" ::: "memory");    \
  __builtin_amdgcn_sched_barrier(0);
#define MFMA_SEG(MB)                                    \
  __builtin_amdgcn_s_setprio(1);                        \
  MFMA32(MB);                                           \
  __builtin_amdgcn_s_setprio(0);

  // one orig-K-tile: 2 halves, 2 barriers total. Stage rotation:
  //  half1: AL(kt)->sAl, B(kt+1)->sB[b^1]; reads sAh+sB[b]
  //         mid: vmcnt(4) confirms AL (oldest 4 of 8), barrier (sAh WAR gate)
  //  half2: AH(kt+1)->sAh; reads sAl (B regs reused)
  //         end: vmcnt(0) confirms B+AH, barrier
#define TILE_BODY(KT)                                           \
  {                                                             \
    const int b = (KT) & 1;                                     \
    const int bn1 = b ^ 1;                                      \
    const int kp1 = ((KT) + 1 < NTO) ? ((KT) + 1) : (NTO - 1);  \
    /* ---- half 1: hi ---- */                                  \
    STAGE_AL(KT, 0);                                            \
    STAGE_AL(KT, 1);                                            \
    STAGE_B(kp1, 0, bn1);                                       \
    STAGE_B(kp1, 1, bn1);                                       \
    LOAD_A0(sAh, 0);                                            \
    LOAD_A1(sAh, 0);                                            \
    LOAD_B0(b);                                                 \
    LOAD_B1(b);                                                 \
    WAITK();                                                    \
    MFMA_SEG(0);                                                \
    LOAD_A0(sAh, 4);                                            \
    LOAD_A1(sAh, 4);                                            \
    WAITK();                                                    \
    MFMA_SEG(4);                                                \
    asm volatile("s_waitcnt vmcnt(4)" ::: "memory");            \
    __builtin_amdgcn_s_barrier();                               \
    /* ---- half 2: lo (B regs reused) ---- */                  \
    STAGE_AH(kp1, 0);                                           \
    STAGE_AH(kp1, 1);                                           \
    LOAD_A0(sAl, 0);                                            \
    LOAD_A1(sAl, 0);                                            \
    WAITK();                                                    \
    MFMA_SEG(0);                                                \
    LOAD_A0(sAl, 4);                                            \
    LOAD_A1(sAl, 4);                                            \
    WAITK();                                                    \
    MFMA_SEG(4);                                                \
    asm volatile("s_waitcnt vmcnt(0)" ::: "memory");            \
    __builtin_amdgcn_s_barrier();                               \
  }

  // prologue: AH(0) + B(0) into sB[0]; AL(0) staged in-loop at half 1
  STAGE_AH(0, 0);
  STAGE_AH(0, 1);
  STAGE_B(0, 0, 0);
  STAGE_B(0, 1, 0);
  asm volatile("s_waitcnt vmcnt(0)" ::: "memory");
  __builtin_amdgcn_s_barrier();

  for (int i2 = 0; i2 < NTO / 2; ++i2) {
    TILE_BODY(2 * i2);
    TILE_BODY(2 * i2 + 1);
  }

  asm volatile("s_waitcnt vmcnt(0)" ::: "memory");

  // epilogue: C/D layout col=lane&15, row=(lane>>4)*4+reg [m89/m91]
  const int rowg = (lane >> 4) * 4;
#pragma unroll
  for (int n = 0; n < 4; ++n) {
    const int col = bn + (w & 3) * 64 + n * 16 + r15;
    const float bv = bias[col];
#pragma unroll
    for (int m = 0; m < 8; ++m) {
      const int row0 = bm + (w >> 2) * 128 + m * 16 + rowg;
#pragma unroll
      for (int k = 0; k < 4; ++k)
        out[(size_t)(row0 + k) * N_DIM + col] = acc[m][n][k] + bv;
    }
  }
}

// ---------- fallback (workspace too small): fp32 tiled ----------
__global__ void fallback_gemm(const float* __restrict__ x,
                              const float* __restrict__ w,
                              const float* __restrict__ bias,
                              float* __restrict__ out) {
  __shared__ float sx[16][17];
  __shared__ float sw[16][17];
  int tx = threadIdx.x & 15, ty = threadIdx.x >> 4;
  int m = blockIdx.y * 16 + ty;
  int n = blockIdx.x * 16 + tx;
  float acc = 0.f;
  for (int k0 = 0; k0 < K_DIM; k0 += 16) {
    sx[ty][tx] = x[(size_t)m * K_DIM + k0 + tx];
    float wv = w[(size_t)(blockIdx.x * 16 + ty) * K_DIM + k0 + tx];
    sw[ty][tx] = (wv > 0.f) ? 1.f : ((wv < 0.f) ? -1.f : 0.f);
    __syncthreads();
#pragma unroll
    for (int kk = 0; kk < 16; ++kk) acc += sx[ty][kk] * sw[tx][kk];
    __syncthreads();
  }
  out[(size_t)m * N_DIM + n] = acc + bias[n];
}

extern "C" void kernel_launch(void* const* d_in, const int* in_sizes, int n_in,
                              void* d_out, int out_size, void* d_ws,
                              size_t ws_size, hipStream_t stream) {
  const float* x = (const float*)d_in[0];
  const float* w = (const float*)d_in[1];
  const float* bias = (const float*)d_in[2];
  float* out = (float*)d_out;

  const size_t elems = (size_t)N_DIM * K_DIM;
  const size_t need = elems * 2u * 3u;  // Sb + A'(hi|lo) bf16 = 96 MiB

  if (ws_size < need) {
    dim3 grid(N_DIM / 16, M_DIM / 16);
    fallback_gemm<<<grid, 256, 0, stream>>>(x, w, bias, out);
    return;
  }

  uint16_t* Sb = (uint16_t*)d_ws;  // [4096][4096] sign(W) bf16
  uint16_t* Ab = Sb + elems;       // [4096][8192] (x_hi | x_lo) bf16

  const int n8 = (int)(elems / 8);
  convert_fused<<<4096, 256, 0, stream>>>((const u32x4*)w, (u16x8*)Sb,
                                          (const f4*)x, Ab, n8);

  bingemm8<<<dim3(256), 512, 0, stream>>>(Ab, Sb, bias, out);
}